// Round 1
// baseline (111.638 us; speedup 1.0000x reference)
//
#include <hip/hip_runtime.h>

// out[b, t] = x[b] * r^t,  r = 1.0 + (0.99 - 1.0) * delta_t  (computed in f64,
// cast to f32, matching the reference's Python-double -> f32 path).
// Output layout: (B, steps, 1) row-major fp32 -> out[b*steps + t].
//
// Write-BW-bound: 512 MiB stored per call. Strategy: one float4 (4 t-values)
// per thread per iteration; thread's t-position fixed, grid-stride over b so
// the expensive power r^(4*tq) is computed ONCE per thread (f64 for accuracy).

__global__ __launch_bounds__(256) void air_res_vec4(
    const float* __restrict__ x,
    const float* __restrict__ dt_p,
    float4* __restrict__ out,   // out_size/4 float4s
    int B, int steps4)          // steps4 = steps/4
{
    const long long tid      = (long long)blockIdx.x * blockDim.x + threadIdx.x;
    const long long nthreads = (long long)gridDim.x * blockDim.x;

    // Precondition (checked on host): nthreads % steps4 == 0, so tq is
    // invariant across the b-stride loop.
    int b        = (int)(tid / steps4);
    const int tq = (int)(tid % steps4);
    const int bstep = (int)(nthreads / steps4);

    const double COEF = 0.99 - 1.0;              // exact reference constant
    const double rd   = 1.0 + COEF * (double)dt_p[0];
    const float  rf   = (float)rd;
    // r^(4*tq) in double, then cast. t up to 4095 -> f64 keeps error ~1 ulp f32.
    const float  p    = (float)exp2((double)(4 * tq) * log2(rd));

    for (; b < B; b += bstep) {
        const float v0 = x[b] * p;
        const float v1 = v0 * rf;
        const float v2 = v1 * rf;
        const float v3 = v2 * rf;
        out[(long long)b * steps4 + tq] = make_float4(v0, v1, v2, v3);
    }
}

// Generic scalar fallback (any steps / grid shape). One element per thread,
// grid-stride; power computed in f64 per element (slow but correct).
__global__ __launch_bounds__(256) void air_res_scalar(
    const float* __restrict__ x,
    const float* __restrict__ dt_p,
    float* __restrict__ out,
    int B, int steps)
{
    const long long total    = (long long)B * steps;
    const long long nthreads = (long long)gridDim.x * blockDim.x;
    const double COEF = 0.99 - 1.0;
    const double rd   = 1.0 + COEF * (double)dt_p[0];
    const double l2r  = log2(rd);

    for (long long i = (long long)blockIdx.x * blockDim.x + threadIdx.x;
         i < total; i += nthreads) {
        const int b = (int)(i / steps);
        const int t = (int)(i % steps);
        out[i] = x[b] * (float)exp2((double)t * l2r);
    }
}

extern "C" void kernel_launch(void* const* d_in, const int* in_sizes, int n_in,
                              void* d_out, int out_size, void* d_ws, size_t ws_size,
                              hipStream_t stream) {
    // Inputs (setup_inputs order): steps (int scalar, on device — unused),
    // x (float32, B elements), delta_t (float32 scalar, on device).
    const float* x    = (const float*)d_in[1];
    const float* dt_p = (const float*)d_in[2];
    float* out        = (float*)d_out;

    const int B     = in_sizes[1];
    const int steps = out_size / B;   // 4096

    const int threads = 256;
    const int blocks  = 2048;         // 524288 threads, grid-stride over b

    const long long nthreads = (long long)blocks * threads;
    if ((steps % 4) == 0 && (nthreads % (steps / 4)) == 0) {
        air_res_vec4<<<blocks, threads, 0, stream>>>(
            x, dt_p, (float4*)out, B, steps / 4);
    } else {
        air_res_scalar<<<blocks, threads, 0, stream>>>(x, dt_p, out, B, steps);
    }
}

// Round 2
// 96.900 us; speedup vs baseline: 1.1521x; 1.1521x over previous
//
#include <hip/hip_runtime.h>

// out[b, t] = x[b] * r^t,  r = 1.0 + (0.99 - 1.0) * delta_t  (f64 -> f32,
// matching the reference's Python-double -> f32 path).
// Output layout: (B, steps, 1) row-major fp32 -> out[b*steps + t].
//
// Write-BW-bound: 512 MiB stored. R1 hit 4.8 TB/s vs fill's 6.74 TB/s on the
// same chip -> per-iteration x[b] load + dependent mul chain throttled store
// issue. R2: each thread owns 4 consecutive rows/iter (one float4 x load),
// per-thread scale factors hoisted, 4 independent nontemporal float4 stores,
// pointer-increment addressing. 16 loop trips instead of 64.

typedef float vfloat4 __attribute__((ext_vector_type(4)));

__global__ __launch_bounds__(256) void air_res_vec4x4(
    const float4* __restrict__ xv,   // B/4 float4s
    const float* __restrict__ dt_p,
    float* __restrict__ out,
    int B4, int steps4)              // B/4, steps/4
{
    const long long tid      = (long long)blockIdx.x * blockDim.x + threadIdx.x;
    const long long nthreads = (long long)gridDim.x * blockDim.x;

    // Host guarantees nthreads % steps4 == 0 -> tq invariant over the b-loop.
    int g        = (int)(tid / steps4);        // row-quad group
    const int tq = (int)(tid % steps4);
    const int gstep = (int)(nthreads / steps4);

    const double COEF = 0.99 - 1.0;            // exact reference constant
    const double rd   = 1.0 + COEF * (double)dt_p[0];
    const float  rf   = (float)rd;
    // r^(4*tq) in f64: t up to 4095 keeps the cast-to-f32 error ~1 ulp.
    const float s0 = (float)exp2((double)(4 * tq) * log2(rd));
    const float s1 = s0 * rf;
    const float s2 = s1 * rf;
    const float s3 = s2 * rf;

    const long long rowq_stride = 4LL * steps4;          // float4s per 4 rows... in floats: 4 rows * steps floats = 4*4*steps4
    for (; g < B4; g += gstep) {
        const float4 xb = xv[g];                         // x[4g .. 4g+3], aligned 16B
        float* p = out + (long long)(4 * g) * (long long)(4 * steps4) + 4LL * tq;

        vfloat4 o;
        o = (vfloat4){xb.x * s0, xb.x * s1, xb.x * s2, xb.x * s3};
        __builtin_nontemporal_store(o, (vfloat4*)p);
        o = (vfloat4){xb.y * s0, xb.y * s1, xb.y * s2, xb.y * s3};
        __builtin_nontemporal_store(o, (vfloat4*)(p + 4LL * steps4));
        o = (vfloat4){xb.z * s0, xb.z * s1, xb.z * s2, xb.z * s3};
        __builtin_nontemporal_store(o, (vfloat4*)(p + 8LL * steps4));
        o = (vfloat4){xb.w * s0, xb.w * s1, xb.w * s2, xb.w * s3};
        __builtin_nontemporal_store(o, (vfloat4*)(p + 12LL * steps4));
    }
    (void)rowq_stride;
}

// Generic scalar fallback (any shape). One element per thread, grid-stride.
__global__ __launch_bounds__(256) void air_res_scalar(
    const float* __restrict__ x,
    const float* __restrict__ dt_p,
    float* __restrict__ out,
    int B, int steps)
{
    const long long total    = (long long)B * steps;
    const long long nthreads = (long long)gridDim.x * blockDim.x;
    const double COEF = 0.99 - 1.0;
    const double rd   = 1.0 + COEF * (double)dt_p[0];
    const double l2r  = log2(rd);

    for (long long i = (long long)blockIdx.x * blockDim.x + threadIdx.x;
         i < total; i += nthreads) {
        const int b = (int)(i / steps);
        const int t = (int)(i % steps);
        out[i] = x[b] * (float)exp2((double)t * l2r);
    }
}

extern "C" void kernel_launch(void* const* d_in, const int* in_sizes, int n_in,
                              void* d_out, int out_size, void* d_ws, size_t ws_size,
                              hipStream_t stream) {
    // Inputs (setup_inputs order): steps (scalar, unused on host side),
    // x (float32, B elements), delta_t (float32 scalar, on device).
    const float* x    = (const float*)d_in[1];
    const float* dt_p = (const float*)d_in[2];
    float* out        = (float*)d_out;

    const int B     = in_sizes[1];
    const int steps = out_size / B;   // 4096

    const int threads = 256;
    const int blocks  = 2048;         // 524288 threads
    const long long nthreads = (long long)blocks * threads;

    if ((steps % 4) == 0 && (B % 4) == 0 &&
        (nthreads % (steps / 4)) == 0) {
        air_res_vec4x4<<<blocks, threads, 0, stream>>>(
            (const float4*)x, dt_p, out, B / 4, steps / 4);
    } else {
        air_res_scalar<<<blocks, threads, 0, stream>>>(x, dt_p, out, B, steps);
    }
}

// Round 3
// 95.771 us; speedup vs baseline: 1.1657x; 1.0118x over previous
//
#include <hip/hip_runtime.h>

// out[b, t] = x[b] * r^t,  r = 1.0 + (0.99 - 1.0) * delta_t  (f64 -> f32,
// matching the reference's Python-double -> f32 path).
// Output layout: (B, steps, 1) row-major fp32 -> out[b*steps + t].
//
// Write-BW-bound: 512 MiB stored. Ladder: R1 scalar-load+dep-chain 4.8 TB/s;
// R2 float4-x-load + 4 independent NT float4 stores -> 5.54 TB/s. Fill kernel
// on same chip: 6.74-6.93 TB/s with PLAIN stores. R3 A/B: drop the
// nontemporal flag (nt = no-allocate in TCC; hypothesis: bypasses L2 write
// coalescing and drains slower). Everything else unchanged.

typedef float vfloat4 __attribute__((ext_vector_type(4)));

__global__ __launch_bounds__(256) void air_res_vec4x4(
    const float4* __restrict__ xv,   // B/4 float4s
    const float* __restrict__ dt_p,
    float* __restrict__ out,
    int B4, int steps4)              // B/4, steps/4
{
    const long long tid      = (long long)blockIdx.x * blockDim.x + threadIdx.x;
    const long long nthreads = (long long)gridDim.x * blockDim.x;

    // Host guarantees nthreads % steps4 == 0 -> tq invariant over the b-loop.
    int g        = (int)(tid / steps4);        // row-quad group
    const int tq = (int)(tid % steps4);
    const int gstep = (int)(nthreads / steps4);

    const double COEF = 0.99 - 1.0;            // exact reference constant
    const double rd   = 1.0 + COEF * (double)dt_p[0];
    const float  rf   = (float)rd;
    // r^(4*tq) in f64: t up to 4095 keeps the cast-to-f32 error ~1 ulp.
    const float s0 = (float)exp2((double)(4 * tq) * log2(rd));
    const float s1 = s0 * rf;
    const float s2 = s1 * rf;
    const float s3 = s2 * rf;

    for (; g < B4; g += gstep) {
        const float4 xb = xv[g];               // x[4g .. 4g+3], aligned 16B
        float* p = out + (long long)(4 * g) * (long long)(4 * steps4) + 4LL * tq;

        *(vfloat4*)p =
            (vfloat4){xb.x * s0, xb.x * s1, xb.x * s2, xb.x * s3};
        *(vfloat4*)(p + 4LL * steps4) =
            (vfloat4){xb.y * s0, xb.y * s1, xb.y * s2, xb.y * s3};
        *(vfloat4*)(p + 8LL * steps4) =
            (vfloat4){xb.z * s0, xb.z * s1, xb.z * s2, xb.z * s3};
        *(vfloat4*)(p + 12LL * steps4) =
            (vfloat4){xb.w * s0, xb.w * s1, xb.w * s2, xb.w * s3};
    }
}

// Generic scalar fallback (any shape). One element per thread, grid-stride.
__global__ __launch_bounds__(256) void air_res_scalar(
    const float* __restrict__ x,
    const float* __restrict__ dt_p,
    float* __restrict__ out,
    int B, int steps)
{
    const long long total    = (long long)B * steps;
    const long long nthreads = (long long)gridDim.x * blockDim.x;
    const double COEF = 0.99 - 1.0;
    const double rd   = 1.0 + COEF * (double)dt_p[0];
    const double l2r  = log2(rd);

    for (long long i = (long long)blockIdx.x * blockDim.x + threadIdx.x;
         i < total; i += nthreads) {
        const int b = (int)(i / steps);
        const int t = (int)(i % steps);
        out[i] = x[b] * (float)exp2((double)t * l2r);
    }
}

extern "C" void kernel_launch(void* const* d_in, const int* in_sizes, int n_in,
                              void* d_out, int out_size, void* d_ws, size_t ws_size,
                              hipStream_t stream) {
    // Inputs (setup_inputs order): steps (scalar, unused on host side),
    // x (float32, B elements), delta_t (float32 scalar, on device).
    const float* x    = (const float*)d_in[1];
    const float* dt_p = (const float*)d_in[2];
    float* out        = (float*)d_out;

    const int B     = in_sizes[1];
    const int steps = out_size / B;   // 4096

    const int threads = 256;
    const int blocks  = 2048;         // 524288 threads
    const long long nthreads = (long long)blocks * threads;

    if ((steps % 4) == 0 && (B % 4) == 0 &&
        (nthreads % (steps / 4)) == 0) {
        air_res_vec4x4<<<blocks, threads, 0, stream>>>(
            (const float4*)x, dt_p, out, B / 4, steps / 4);
    } else {
        air_res_scalar<<<blocks, threads, 0, stream>>>(x, dt_p, out, B, steps);
    }
}